// Round 10
// baseline (236.921 us; speedup 1.0000x reference)
//
#include <hip/hip_runtime.h>
#include <cstdint>
#include <cstddef>

#define N_NODES 50000
#define N_EDGES 400000
#define E_TOT   (N_EDGES + N_NODES)   // with self-loops
#define D_INF   128
#define C1      256                   // 8 heads * 32
#define HIDC    32
#define OUTC    16
#define NEG_SLOPE 0.2f
#define LOG2E   1.44269504088896340736f

// Fixed-capacity CSR: 64 slots per node (deg ~ Poisson(9); P(deg>64) ~ 1e-33).
// esrc[dst*64 + pos], pos from atomicAdd on deg (deg doubles as cursor).
#define SEG_CAP 64

#define SCAT_T  (N_EDGES / 4)                   // 100000 edge-batch threads (4 edges each)
#define SLOOP_T ((N_NODES + 3) / 4)             // 12500 self-loop threads
#define SCATB   ((SCAT_T + SLOOP_T + 255) / 256)  // 440 scatter blocks
#define UNITS16 (N_NODES / 16)                  // 3125 16-row units (exact)
#define U16PAD  (UNITS16 + 1)                   // +1 pad unit for 32-row tail reads
#define NU32    ((N_NODES + 31) / 32)           // 1563 32-row units
#define XPB     UNITS16                         // 3125 x-pack blocks (1 unit/block)
#define WPB     40                              // (2*4096 + 2*1024)/256 weight-pack blocks
#define PREPB   (SCATB + XPB + WPB)
#define GBLK    ((2 * NU32 + 3) / 4)            // 782 GEMM blocks (4 waves each)
#define GAT1B   ((N_NODES / 2 + 3) / 4)         // 6250: one wave per dst-PAIR

typedef __bf16 bf16x8 __attribute__((ext_vector_type(8)));
typedef float  floatx4 __attribute__((ext_vector_type(4)));
typedef float  floatx2 __attribute__((ext_vector_type(2)));
typedef int    intx4  __attribute__((ext_vector_type(4)));
typedef unsigned int uintx4 __attribute__((ext_vector_type(4)));
typedef unsigned int uintx2 __attribute__((ext_vector_type(2)));
typedef unsigned short ushortx8 __attribute__((ext_vector_type(8)));
typedef unsigned short ushortx4 __attribute__((ext_vector_type(4)));

__device__ __forceinline__ unsigned short f2bf(float f) {
  unsigned int u = __builtin_bit_cast(unsigned int, f);
  u += 0x7FFFu + ((u >> 16) & 1u);   // RNE (finite values)
  return (unsigned short)(u >> 16);
}
__device__ __forceinline__ float bf2f(unsigned short u) {
  return __builtin_bit_cast(float, (unsigned int)u << 16);
}
// packed bf16x2 word -> float2 (channels 2j, 2j+1)
__device__ __forceinline__ floatx2 bf2x2(unsigned int u) {
  floatx2 r;
  r.x = __builtin_bit_cast(float, u << 16);
  r.y = __builtin_bit_cast(float, u & 0xffff0000u);
  return r;
}

// ---------- prep: 4-edge-batched CSR scatter + x->A-frag pack + W->B-frag packs ----------
// Scatter blocks FIRST (long pole). 4 edges/thread via aligned int4 loads; 4
// independent returning atomics in flight. int64-vs-int32 edge_index detected
// per block from the first 64 odd words (L2-hot).
// Fragment layout (MFMA 16x16x32 bf16): frag index ((u*KB)+kb)*64+lane,
// lane = q*16+lo; 8 elems/lane: A row u*16+lo, k = kb*32+q*8+j;
//                             B col nt*16+lo, k = kb*32+q*8+j.
__global__ __launch_bounds__(256) void k_prep(
    const int* __restrict__ ei,
    const float* __restrict__ x, unsigned short* __restrict__ xpack,
    const float* __restrict__ W1l, const float* __restrict__ W1r,
    const float* __restrict__ W2l, const float* __restrict__ W2r,
    unsigned short* __restrict__ w1lp, unsigned short* __restrict__ w1rp,
    unsigned short* __restrict__ w2lp, unsigned short* __restrict__ w2rp,
    int* __restrict__ deg, int* __restrict__ esrc) {
  const int bid = blockIdx.x;
  const int tid = threadIdx.x;
  if (bid < SCATB) {
    __shared__ int sdet;
    if (tid == 0) sdet = 0;
    __syncthreads();
    if (tid < 64) atomicOr(&sdet, ei[2 * tid + 1]);
    __syncthreads();
    const bool f64 = (sdet == 0);   // int64 iff all sampled odd words zero

    const int t = bid * 256 + tid;
    int s4[4], d4[4];
    bool valid = false;
    if (t < SCAT_T) {
      valid = true;
      if (f64) {
        intx4 a = *reinterpret_cast<const intx4*>(ei + 8 * t);
        intx4 b = *reinterpret_cast<const intx4*>(ei + 8 * t + 4);
        intx4 c = *reinterpret_cast<const intx4*>(ei + 2 * N_EDGES + 8 * t);
        intx4 d = *reinterpret_cast<const intx4*>(ei + 2 * N_EDGES + 8 * t + 4);
        s4[0] = a.x; s4[1] = a.z; s4[2] = b.x; s4[3] = b.z;
        d4[0] = c.x; d4[1] = c.z; d4[2] = d.x; d4[3] = d.z;
      } else {
        intx4 a = *reinterpret_cast<const intx4*>(ei + 4 * t);
        intx4 c = *reinterpret_cast<const intx4*>(ei + N_EDGES + 4 * t);
        s4[0] = a.x; s4[1] = a.y; s4[2] = a.z; s4[3] = a.w;
        d4[0] = c.x; d4[1] = c.y; d4[2] = c.z; d4[3] = c.w;
      }
    } else if (t < SCAT_T + SLOOP_T) {
      valid = true;
      const int n0 = (t - SCAT_T) * 4;   // N_NODES = 4*SLOOP_T exactly
      s4[0] = d4[0] = n0;     s4[1] = d4[1] = n0 + 1;
      s4[2] = d4[2] = n0 + 2; s4[3] = d4[3] = n0 + 3;
    }
    if (valid) {
      int pos[4];
#pragma unroll
      for (int j = 0; j < 4; ++j) {
        const bool ok = (unsigned)s4[j] < N_NODES && (unsigned)d4[j] < N_NODES;
        pos[j] = ok ? atomicAdd(&deg[d4[j]], 1) : SEG_CAP;
      }
#pragma unroll
      for (int j = 0; j < 4; ++j)
        if (pos[j] < SEG_CAP) esrc[((size_t)d4[j] << 6) + pos[j]] = s4[j];
    }
    return;
  }
  if (bid < SCATB + XPB) {
    // one 16-row unit per block: 4 kb * 64 lanes = 256 threads
    const int u = bid - SCATB;
    const int kb = tid >> 6, lane = tid & 63;
    const int row = u * 16 + (lane & 15);
    const int k0 = kb * 32 + (lane >> 4) * 8;
    floatx4 a = *reinterpret_cast<const floatx4*>(x + (size_t)row * D_INF + k0);
    floatx4 b = *reinterpret_cast<const floatx4*>(x + (size_t)row * D_INF + k0 + 4);
    ushortx8 u8;
#pragma unroll
    for (int j = 0; j < 4; ++j) { u8[j] = f2bf(a[j]); u8[4 + j] = f2bf(b[j]); }
    *reinterpret_cast<ushortx8*>(xpack + ((size_t)(u * 4 + kb) * 64 + lane) * 8) = u8;
    return;
  }
  int f = (bid - SCATB - XPB) * 256 + tid;
  if (f < 8192) {                     // W1l frags [0,4096), W1r [4096,8192)
    const float* W = (f < 4096) ? W1l : W1r;
    unsigned short* P = (f < 4096) ? w1lp : w1rp;
    f &= 4095;
    const int nt = f >> 8, kb = (f >> 6) & 3, lane = f & 63;
    const int col = nt * 16 + (lane & 15);
    const int k0 = kb * 32 + (lane >> 4) * 8;
    ushortx8 u8;
#pragma unroll
    for (int j = 0; j < 8; ++j) u8[j] = f2bf(W[(size_t)(k0 + j) * C1 + col]);
    *reinterpret_cast<ushortx8*>(P + (size_t)f * 8) = u8;
  } else {                            // W2l frags [0,1024), W2r [1024,2048)
    f -= 8192;
    const float* W = (f < 1024) ? W2l : W2r;
    unsigned short* P = (f < 1024) ? w2lp : w2rp;
    f &= 1023;
    const int nt = f >> 9, kb = (f >> 6) & 7, lane = f & 63;
    const int col = nt * 16 + (lane & 15);
    const int k0 = kb * 32 + (lane >> 4) * 8;
    ushortx8 u8;
#pragma unroll
    for (int j = 0; j < 8; ++j) u8[j] = f2bf(W[(size_t)(k0 + j) * HIDC + col]);
    *reinterpret_cast<ushortx8*>(P + (size_t)f * 8) = u8;
  }
}

// ---------- coalesced fragment load: lane i reads base + i*16B ----------
__device__ __forceinline__ bf16x8 ldfrag(const unsigned short* base, int lane) {
  uintx4 raw = *reinterpret_cast<const uintx4*>(base + (size_t)lane * 8);
  return __builtin_bit_cast(bf16x8, raw);
}

// ---------- 32-row single-output GEMM from fragment-packed operands ----------
template <int KB, int NCOLS>
__device__ __forceinline__ void gemm_body32(
    int u, int lane, const unsigned short* __restrict__ Ap,
    const unsigned short* __restrict__ Bp, unsigned short* __restrict__ C) {
  const int lo = lane & 15;
  const int q  = lane >> 4;
  const int r0 = u * 32;
  const bool two = (r0 + 16) < N_NODES;   // tail unit: rg1 is pad

  bf16x8 af[2][KB];
#pragma unroll
  for (int rg = 0; rg < 2; ++rg)
#pragma unroll
    for (int kb = 0; kb < KB; ++kb)
      af[rg][kb] = ldfrag(Ap + ((size_t)(u * 2 + rg) * KB + kb) * 64 * 8, lane);

#pragma unroll 4
  for (int nt = 0; nt < NCOLS / 16; ++nt) {
    bf16x8 b[KB];
#pragma unroll
    for (int kb = 0; kb < KB; ++kb)
      b[kb] = ldfrag(Bp + ((size_t)nt * KB + kb) * 64 * 8, lane);
    floatx4 acc0 = {0.f, 0.f, 0.f, 0.f};
    floatx4 acc1 = {0.f, 0.f, 0.f, 0.f};
#pragma unroll
    for (int kb = 0; kb < KB; ++kb) {
      acc0 = __builtin_amdgcn_mfma_f32_16x16x32_bf16(af[0][kb], b[kb], acc0, 0, 0, 0);
      acc1 = __builtin_amdgcn_mfma_f32_16x16x32_bf16(af[1][kb], b[kb], acc1, 0, 0, 0);
    }
    // C/D layout: col = lane&15, row = (lane>>4)*4 + reg   [m89-verified]
#pragma unroll
    for (int r = 0; r < 4; ++r) {
      C[(size_t)(r0 + q * 4 + r) * NCOLS + nt * 16 + lo] = f2bf(acc0[r]);
      if (two)
        C[(size_t)(r0 + 16 + q * 4 + r) * NCOLS + nt * 16 + lo] = f2bf(acc1[r]);
    }
  }
}

// ---------- GEMM1: xpack x (w1lp,w1rp) -> xl1, xr1 (row-major) ----------
__global__ __launch_bounds__(256) void k_gemm1(
    const unsigned short* __restrict__ Ap,
    const unsigned short* __restrict__ B0, const unsigned short* __restrict__ B1,
    unsigned short* __restrict__ C0, unsigned short* __restrict__ C1_) {
  const int wave = threadIdx.x >> 6;
  const int lane = threadIdx.x & 63;
  const int unit = blockIdx.x * 4 + wave;
  if (unit >= 2 * NU32) return;
  const int o = (unit >= NU32) ? 1 : 0;
  gemm_body32<4, C1>(unit - o * NU32, lane, Ap, o ? B1 : B0, o ? C1_ : C0);
}

// ---------- GEMM2: h1pack x (w2lp,w2rp) -> xl2, xr2 (row-major) ----------
__global__ __launch_bounds__(256) void k_gemm2(
    const unsigned short* __restrict__ Ap,
    const unsigned short* __restrict__ B0, const unsigned short* __restrict__ B1,
    unsigned short* __restrict__ C0, unsigned short* __restrict__ C1_) {
  const int wave = threadIdx.x >> 6;
  const int lane = threadIdx.x & 63;
  const int unit = blockIdx.x * 4 + wave;
  if (unit >= 2 * NU32) return;
  const int o = (unit >= NU32) ? 1 : 0;
  gemm_body32<8, HIDC>(unit - o * NU32, lane, Ap, o ? B1 : B0, o ? C1_ : C0);
}

// ---------- GAT layer 1: TWO adjacent dsts per wave, lockstep ----------
// Wave owns d0=2p, d1=2p+1 (adjacent -> shared cache lines for xr/esrc).
// Half h = lane>>5 processes alternating edge slots of BOTH dsts; lane w
// owns channels w*8..w*8+7. 4 gathers in flight (2 per dst, ping-pong).
// Shorter segment's tail slots masked via p*{0,1} (stale buffers hold a
// finite previously-loaded row or zeros -> no NaN). No softmax max-tracking
// (scores tiny; med3 clamp insurance). log2e folded into att.
// Output written directly in GEMM2 A-fragment order to h1pack.
__global__ __launch_bounds__(256) void k_gat1(
    const unsigned short* __restrict__ xl1, const unsigned short* __restrict__ xr1,
    const float* __restrict__ att1, const float* __restrict__ bi1,
    const int* __restrict__ deg, const int* __restrict__ esrc,
    unsigned short* __restrict__ h1pack) {
  const int wave = threadIdx.x >> 6;
  const int lane = threadIdx.x & 63;
  const int pr = blockIdx.x * 4 + wave;
  const int d0 = pr * 2;
  if (d0 >= N_NODES) return;
  const int d1 = d0 + 1;                 // N_NODES even -> always valid
  const int h = lane >> 5;
  const int w = lane & 31;
  const int cb = w * 8;
  const unsigned cb2 = (unsigned)cb * 2u;
  const char* __restrict__ xbase = (const char*)xl1;

  floatx2 att2v[4], xr0v[4], xr1v[4];
  {
    uintx4 r0 = *reinterpret_cast<const uintx4*>(xr1 + (size_t)d0 * C1 + cb);
    uintx4 r1 = *reinterpret_cast<const uintx4*>(xr1 + (size_t)d1 * C1 + cb);
    floatx4 a0 = *reinterpret_cast<const floatx4*>(att1 + cb);
    floatx4 a1 = *reinterpret_cast<const floatx4*>(att1 + cb + 4);
#pragma unroll
    for (int j = 0; j < 4; ++j) { xr0v[j] = bf2x2(r0[j]); xr1v[j] = bf2x2(r1[j]); }
    att2v[0] = floatx2{a0.x, a0.y} * LOG2E;
    att2v[1] = floatx2{a0.z, a0.w} * LOG2E;
    att2v[2] = floatx2{a1.x, a1.y} * LOG2E;
    att2v[3] = floatx2{a1.z, a1.w} * LOG2E;
  }

  const int n0 = min(deg[d0], SEG_CAP);
  const int n1 = min(deg[d1], SEG_CAP);
  const int nm = max(n0, n1);
  const int* __restrict__ ep0 = esrc + ((size_t)d0 << 6);
  const int* __restrict__ ep1 = esrc + ((size_t)d1 << 6);

  float l0 = 0.f, l1 = 0.f;
  floatx2 acc0[4] = {{0.f,0.f},{0.f,0.f},{0.f,0.f},{0.f,0.f}};
  floatx2 acc1[4] = {{0.f,0.f},{0.f,0.f},{0.f,0.f},{0.f,0.f}};

  auto L = [&](const int* ep, int idx) {
    const unsigned off = ((unsigned)ep[idx] << 9) + cb2;
    return *reinterpret_cast<const uintx4*>(xbase + off);
  };
  auto score = [&](uintx4 cur, const floatx2* xrv, floatx2* xs2) -> float {
    floatx2 v2 = {0.f, 0.f};
#pragma unroll
    for (int j = 0; j < 4; ++j) {
      xs2[j] = bf2x2(cur[j]);
      floatx2 s2 = xs2[j] + xrv[j];
      floatx2 e2 = __builtin_elementwise_max(s2, s2 * NEG_SLOPE);   // leaky
      v2 = __builtin_elementwise_fma(e2, att2v[j], v2);
    }
    float v = v2.x + v2.y;
    v += __shfl_xor(v, 1);
    v += __shfl_xor(v, 2);            // 4-lane group = one head
    return __builtin_amdgcn_exp2f(__builtin_amdgcn_fmed3f(v, -100.f, 100.f));
  };
  auto pass = [&](uintx4 c0, uintx4 c1, bool k0, bool k1) {
    floatx2 xs0[4], xs1[4];
    const float p0 = score(c0, xr0v, xs0) * (k0 ? 1.f : 0.f);
    const float p1 = score(c1, xr1v, xs1) * (k1 ? 1.f : 0.f);
    l0 += p0; l1 += p1;
    const floatx2 q0 = {p0, p0}, q1 = {p1, p1};
#pragma unroll
    for (int j = 0; j < 4; ++j) {
      acc0[j] = __builtin_elementwise_fma(q0, xs0[j], acc0[j]);
      acc1[j] = __builtin_elementwise_fma(q1, xs1[j], acc1[j]);
    }
  };

  // 2-deep ping-pong per dst: 4 gathers in flight from the prologue on
  uintx4 a0 = {0u,0u,0u,0u}, a1 = {0u,0u,0u,0u};
  uintx4 b0 = {0u,0u,0u,0u}, b1 = {0u,0u,0u,0u};
  if (h < n0)     a0 = L(ep0, h);
  if (h < n1)     a1 = L(ep1, h);
  if (h + 2 < n0) b0 = L(ep0, h + 2);
  if (h + 2 < n1) b1 = L(ep1, h + 2);
  int i = h;
  while (i < nm) {
    pass(a0, a1, i < n0, i < n1);
    if (i + 4 < n0) a0 = L(ep0, i + 4);
    if (i + 4 < n1) a1 = L(ep1, i + 4);
    i += 2;
    if (i >= nm) break;
    pass(b0, b1, i < n0, i < n1);
    if (i + 4 < n0) b0 = L(ep0, i + 4);
    if (i + 4 < n1) b1 = L(ep1, i + 4);
    i += 2;
  }

  // merge the two halves (plain sums; no max bookkeeping)
  l0 += __shfl_xor(l0, 32);
  l1 += __shfl_xor(l1, 32);
#pragma unroll
  for (int j = 0; j < 4; ++j) {
    acc0[j].x += __shfl_xor(acc0[j].x, 32);
    acc0[j].y += __shfl_xor(acc0[j].y, 32);
    acc1[j].x += __shfl_xor(acc1[j].x, 32);
    acc1[j].y += __shfl_xor(acc1[j].y, 32);
  }

  if (h == 0) {
    const float inv0 = 1.f / fmaxf(l0, 1e-16f);
    const float inv1 = 1.f / fmaxf(l1, 1e-16f);
    ushortx8 ob0, ob1;
#pragma unroll
    for (int j = 0; j < 4; ++j) {
      float z00 = acc0[j].x * inv0 + bi1[cb + 2 * j];
      float z01 = acc0[j].y * inv0 + bi1[cb + 2 * j + 1];
      float z10 = acc1[j].x * inv1 + bi1[cb + 2 * j];
      float z11 = acc1[j].y * inv1 + bi1[cb + 2 * j + 1];
      z00 = z00 > 0.f ? z00 : (__expf(z00) - 1.f);   // ELU
      z01 = z01 > 0.f ? z01 : (__expf(z01) - 1.f);
      z10 = z10 > 0.f ? z10 : (__expf(z10) - 1.f);
      z11 = z11 > 0.f ? z11 : (__expf(z11) - 1.f);
      ob0[2 * j]     = f2bf(z00);
      ob0[2 * j + 1] = f2bf(z01);
      ob1[2 * j]     = f2bf(z10);
      ob1[2 * j + 1] = f2bf(z11);
    }
    // fragment-order stores for GEMM2 A (d0, d1 in same 16-row unit)
    const size_t base = ((size_t)(d0 >> 4) * 8 + (cb >> 5)) * 64
                      + ((cb >> 3) & 3) * 16;
    *reinterpret_cast<ushortx8*>(h1pack + (base + (d0 & 15)) * 8) = ob0;
    *reinterpret_cast<ushortx8*>(h1pack + (base + (d1 & 15)) * 8) = ob1;
  }
}

// ---------- GAT layer 2 (1 head, 32 ch) fused with final linear [32x16] ----------
__global__ __launch_bounds__(256) void k_gat2(
    const unsigned short* __restrict__ xl2, const unsigned short* __restrict__ xr2,
    const float* __restrict__ att2, const float* __restrict__ b2,
    const float* __restrict__ Wlin, const float* __restrict__ blin,
    const int* __restrict__ deg, const int* __restrict__ esrc,
    float* __restrict__ out) {
  __shared__ float sh[4][32];
  const int wave = threadIdx.x >> 6;
  const int lane = threadIdx.x & 63;
  const int dst = blockIdx.x * 4 + wave;
  if (dst >= N_NODES) return;
  const int o8 = lane >> 3;   // edge slot (8 edges in flight)
  const int w = lane & 7;     // channel group
  const int cb = w * 4;       // 4 ch = 2 bf16x2 pairs
  const unsigned cb2 = (unsigned)cb * 2u;
  const char* __restrict__ xbase = (const char*)xl2;

  floatx2 xr2v[2], att2v[2];
  {
    uintx2 r = *reinterpret_cast<const uintx2*>(xr2 + (size_t)dst * HIDC + cb);
    floatx4 a = *reinterpret_cast<const floatx4*>(att2 + cb);
    xr2v[0] = bf2x2(r[0]);
    xr2v[1] = bf2x2(r[1]);
    att2v[0] = floatx2{a.x, a.y} * LOG2E;
    att2v[1] = floatx2{a.z, a.w} * LOG2E;
  }

  const int n = min(deg[dst], SEG_CAP);
  const int* __restrict__ ep = esrc + ((size_t)dst << 6);

  float l = 0.f;
  floatx2 acc2[2] = {{0.f, 0.f}, {0.f, 0.f}};

  auto L = [&](int s) {
    const unsigned off = ((unsigned)s << 6) + cb2;   // row = 64 B
    return *reinterpret_cast<const uintx2*>(xbase + off);
  };
  auto process = [&](uintx2 cur) {
    floatx2 xs2[2];
    floatx2 v2 = {0.f, 0.f};
#pragma unroll
    for (int j = 0; j < 2; ++j) {
      xs2[j] = bf2x2(cur[j]);
      floatx2 s2 = xs2[j] + xr2v[j];
      floatx2 e2 = __builtin_elementwise_max(s2, s2 * NEG_SLOPE);
      v2 = __builtin_elementwise_fma(e2, att2v[j], v2);
    }
    float v = v2.x + v2.y;
    v += __shfl_xor(v, 1);
    v += __shfl_xor(v, 2);
    v += __shfl_xor(v, 4);          // 8-lane group = full 32-ch head
    v = __builtin_amdgcn_fmed3f(v, -100.f, 100.f);
    const float p = __builtin_amdgcn_exp2f(v);
    l += p;
    const floatx2 p2 = {p, p};
#pragma unroll
    for (int j = 0; j < 2; ++j)
      acc2[j] = __builtin_elementwise_fma(p2, xs2[j], acc2[j]);
  };

  uintx2 bufa = {0u, 0u}, bufb = {0u, 0u};
  if (o8 < n)     bufa = L(ep[o8]);
  if (o8 + 8 < n) bufb = L(ep[o8 + 8]);
  int i = o8;
  while (i < n) {
    process(bufa);
    if (i + 16 < n) bufa = L(ep[i + 16]);
    i += 8;
    if (i >= n) break;
    process(bufb);
    if (i + 16 < n) bufb = L(ep[i + 16]);
    i += 8;
  }

  // merge 8 octets (plain sums)
#pragma unroll
  for (int k = 8; k < 64; k <<= 1) {
    l += __shfl_xor(l, k);
#pragma unroll
    for (int j = 0; j < 2; ++j) {
      acc2[j].x += __shfl_xor(acc2[j].x, k);
      acc2[j].y += __shfl_xor(acc2[j].y, k);
    }
  }

  if (o8 == 0) {
    const float inv = 1.f / fmaxf(l, 1e-16f);
#pragma unroll
    for (int j = 0; j < 2; ++j) {
      float z0 = acc2[j].x * inv + b2[cb + 2 * j];
      float z1 = acc2[j].y * inv + b2[cb + 2 * j + 1];
      z0 = z0 > 0.f ? z0 : (__expf(z0) - 1.f);   // ELU
      z1 = z1 > 0.f ? z1 : (__expf(z1) - 1.f);
      sh[wave][cb + 2 * j]     = z0;
      sh[wave][cb + 2 * j + 1] = z1;
    }
  }
  if (lane < OUTC) {
    float o = blin[lane];
#pragma unroll
    for (int k = 0; k < 32; ++k)
      o = fmaf(sh[wave][k], Wlin[k * OUTC + lane], o);
    out[(size_t)dst * OUTC + lane] = o;
  }
}

static inline int cdiv(int a, int b) { return (a + b - 1) / b; }

extern "C" void kernel_launch(void* const* d_in, const int* in_sizes, int n_in,
                              void* d_out, int out_size, void* d_ws, size_t ws_size,
                              hipStream_t stream) {
  const float* x    = (const float*)d_in[0];
  const int*   ei   = (const int*)d_in[1];
  const float* W1l  = (const float*)d_in[2];
  const float* W1r  = (const float*)d_in[3];
  const float* att1 = (const float*)d_in[4];
  const float* b1   = (const float*)d_in[5];
  const float* W2l  = (const float*)d_in[6];
  const float* W2r  = (const float*)d_in[7];
  const float* att2 = (const float*)d_in[8];
  const float* b2   = (const float*)d_in[9];
  const float* Wlin = (const float*)d_in[10];
  const float* blin = (const float*)d_in[11];
  float* out = (float*)d_out;

  char* w = (char*)d_ws;
  auto alloc = [&](size_t bytes) -> char* {
    char* p = w;
    w += (bytes + 255) & ~(size_t)255;
    return p;
  };
  // region A: xl1 (row-major, GEMM1 out), later reused for xl2+xr2 (GEMM2 out)
  char* regionA = alloc((size_t)N_NODES * C1 * 2);          // 25.6 MB
  unsigned short* xl1 = (unsigned short*)regionA;
  unsigned short* xl2 = (unsigned short*)regionA;                           // 3.2 MB
  unsigned short* xr2 = (unsigned short*)(regionA + (size_t)N_NODES * HIDC * 2 + 256);
  unsigned short* xr1 = (unsigned short*)alloc((size_t)N_NODES * C1 * 2);   // 25.6 MB
  // fragment-packed operands
  unsigned short* xpack  = (unsigned short*)alloc((size_t)U16PAD * 4 * 64 * 8 * 2); // 12.8 MB
  unsigned short* h1pack = (unsigned short*)alloc((size_t)U16PAD * 8 * 64 * 8 * 2); // 25.6 MB
  unsigned short* w1lp = (unsigned short*)alloc((size_t)4096 * 8 * 2);  // 64 KB
  unsigned short* w1rp = (unsigned short*)alloc((size_t)4096 * 8 * 2);
  unsigned short* w2lp = (unsigned short*)alloc((size_t)1024 * 8 * 2);  // 16 KB
  unsigned short* w2rp = (unsigned short*)alloc((size_t)1024 * 8 * 2);
  int* deg    = (int*)alloc((size_t)N_NODES * 4);
  int* esrc   = (int*)alloc((size_t)N_NODES * SEG_CAP * 4);   // 12.8 MB

  hipMemsetAsync(deg, 0, (size_t)N_NODES * 4, stream);

  // CSR scatter (long pole first) + x frag-pack + weight frag-packs
  k_prep<<<PREPB, 256, 0, stream>>>(ei, x, xpack, W1l, W1r, W2l, W2r,
                                    w1lp, w1rp, w2lp, w2rp, deg, esrc);

  k_gemm1<<<GBLK, 256, 0, stream>>>(xpack, w1lp, w1rp, xl1, xr1);

  k_gat1<<<GAT1B, 256, 0, stream>>>(xl1, xr1, att1, b1, deg, esrc, h1pack);

  k_gemm2<<<GBLK, 256, 0, stream>>>(h1pack, w2lp, w2rp, xl2, xr2);

  k_gat2<<<cdiv(N_NODES, 4), 256, 0, stream>>>(xl2, xr2, att2, b2, Wlin, blin,
                                               deg, esrc, out);
}

// Round 11
// 224.347 us; speedup vs baseline: 1.0560x; 1.0560x over previous
//
#include <hip/hip_runtime.h>
#include <cstdint>
#include <cstddef>

#define N_NODES 50000
#define N_EDGES 400000
#define E_TOT   (N_EDGES + N_NODES)   // with self-loops
#define D_INF   128
#define C1      256                   // 8 heads * 32
#define HIDC    32
#define OUTC    16
#define NEG_SLOPE 0.2f
#define LOG2E   1.44269504088896340736f

// Fixed-capacity CSR: 64 slots per node (deg ~ Poisson(9); P(deg>64) ~ 1e-33).
// esrc[dst*64 + pos], pos from atomicAdd on deg (deg doubles as cursor).
#define SEG_CAP 64

#define SCAT_T  (N_EDGES / 4)                   // 100000 edge-batch threads (4 edges each)
#define SLOOP_T ((N_NODES + 3) / 4)             // 12500 self-loop threads
#define SCATB   ((SCAT_T + SLOOP_T + 255) / 256)  // 440 scatter blocks
#define UNITS16 (N_NODES / 16)                  // 3125 16-row units (exact)
#define U16PAD  (UNITS16 + 1)                   // +1 pad unit for 32-row tail reads
#define NU32    ((N_NODES + 31) / 32)           // 1563 32-row units
#define XPB     UNITS16                         // 3125 x-pack blocks (1 unit/block)
#define WPB     40                              // (2*4096 + 2*1024)/256 weight-pack blocks
#define PREPB   (SCATB + XPB + WPB)
#define GBLK    ((2 * NU32 + 3) / 4)            // 782 GEMM blocks (4 waves each)

typedef __bf16 bf16x8 __attribute__((ext_vector_type(8)));
typedef float  floatx4 __attribute__((ext_vector_type(4)));
typedef float  floatx2 __attribute__((ext_vector_type(2)));
typedef int    intx4  __attribute__((ext_vector_type(4)));
typedef unsigned int uintx4 __attribute__((ext_vector_type(4)));
typedef unsigned int uintx2 __attribute__((ext_vector_type(2)));
typedef unsigned short ushortx8 __attribute__((ext_vector_type(8)));
typedef unsigned short ushortx4 __attribute__((ext_vector_type(4)));

__device__ __forceinline__ unsigned short f2bf(float f) {
  unsigned int u = __builtin_bit_cast(unsigned int, f);
  u += 0x7FFFu + ((u >> 16) & 1u);   // RNE (finite values)
  return (unsigned short)(u >> 16);
}
__device__ __forceinline__ float bf2f(unsigned short u) {
  return __builtin_bit_cast(float, (unsigned int)u << 16);
}
// packed bf16x2 word -> float2 (channels 2j, 2j+1)
__device__ __forceinline__ floatx2 bf2x2(unsigned int u) {
  floatx2 r;
  r.x = __builtin_bit_cast(float, u << 16);
  r.y = __builtin_bit_cast(float, u & 0xffff0000u);
  return r;
}

// ---------- prep: 4-edge-batched CSR scatter + x->A-frag pack + W->B-frag packs ----------
// Scatter blocks FIRST (long pole). 4 edges/thread via aligned int4 loads; 4
// independent returning atomics in flight. int64-vs-int32 edge_index detected
// per block from the first 64 odd words (L2-hot).
// Fragment layout (MFMA 16x16x32 bf16): frag index ((u*KB)+kb)*64+lane,
// lane = q*16+lo; 8 elems/lane: A row u*16+lo, k = kb*32+q*8+j;
//                             B col nt*16+lo, k = kb*32+q*8+j.
__global__ __launch_bounds__(256) void k_prep(
    const int* __restrict__ ei,
    const float* __restrict__ x, unsigned short* __restrict__ xpack,
    const float* __restrict__ W1l, const float* __restrict__ W1r,
    const float* __restrict__ W2l, const float* __restrict__ W2r,
    unsigned short* __restrict__ w1lp, unsigned short* __restrict__ w1rp,
    unsigned short* __restrict__ w2lp, unsigned short* __restrict__ w2rp,
    int* __restrict__ deg, int* __restrict__ esrc) {
  const int bid = blockIdx.x;
  const int tid = threadIdx.x;
  if (bid < SCATB) {
    __shared__ int sdet;
    if (tid == 0) sdet = 0;
    __syncthreads();
    if (tid < 64) atomicOr(&sdet, ei[2 * tid + 1]);
    __syncthreads();
    const bool f64 = (sdet == 0);   // int64 iff all sampled odd words zero

    const int t = bid * 256 + tid;
    int s4[4], d4[4];
    bool valid = false;
    if (t < SCAT_T) {
      valid = true;
      if (f64) {
        intx4 a = *reinterpret_cast<const intx4*>(ei + 8 * t);
        intx4 b = *reinterpret_cast<const intx4*>(ei + 8 * t + 4);
        intx4 c = *reinterpret_cast<const intx4*>(ei + 2 * N_EDGES + 8 * t);
        intx4 d = *reinterpret_cast<const intx4*>(ei + 2 * N_EDGES + 8 * t + 4);
        s4[0] = a.x; s4[1] = a.z; s4[2] = b.x; s4[3] = b.z;
        d4[0] = c.x; d4[1] = c.z; d4[2] = d.x; d4[3] = d.z;
      } else {
        intx4 a = *reinterpret_cast<const intx4*>(ei + 4 * t);
        intx4 c = *reinterpret_cast<const intx4*>(ei + N_EDGES + 4 * t);
        s4[0] = a.x; s4[1] = a.y; s4[2] = a.z; s4[3] = a.w;
        d4[0] = c.x; d4[1] = c.y; d4[2] = c.z; d4[3] = c.w;
      }
    } else if (t < SCAT_T + SLOOP_T) {
      valid = true;
      const int n0 = (t - SCAT_T) * 4;   // N_NODES = 4*SLOOP_T exactly
      s4[0] = d4[0] = n0;     s4[1] = d4[1] = n0 + 1;
      s4[2] = d4[2] = n0 + 2; s4[3] = d4[3] = n0 + 3;
    }
    if (valid) {
      int pos[4];
#pragma unroll
      for (int j = 0; j < 4; ++j) {
        const bool ok = (unsigned)s4[j] < N_NODES && (unsigned)d4[j] < N_NODES;
        pos[j] = ok ? atomicAdd(&deg[d4[j]], 1) : SEG_CAP;
      }
#pragma unroll
      for (int j = 0; j < 4; ++j)
        if (pos[j] < SEG_CAP) esrc[((size_t)d4[j] << 6) + pos[j]] = s4[j];
    }
    return;
  }
  if (bid < SCATB + XPB) {
    // one 16-row unit per block: 4 kb * 64 lanes = 256 threads
    const int u = bid - SCATB;
    const int kb = tid >> 6, lane = tid & 63;
    const int row = u * 16 + (lane & 15);
    const int k0 = kb * 32 + (lane >> 4) * 8;
    floatx4 a = *reinterpret_cast<const floatx4*>(x + (size_t)row * D_INF + k0);
    floatx4 b = *reinterpret_cast<const floatx4*>(x + (size_t)row * D_INF + k0 + 4);
    ushortx8 u8;
#pragma unroll
    for (int j = 0; j < 4; ++j) { u8[j] = f2bf(a[j]); u8[4 + j] = f2bf(b[j]); }
    *reinterpret_cast<ushortx8*>(xpack + ((size_t)(u * 4 + kb) * 64 + lane) * 8) = u8;
    return;
  }
  int f = (bid - SCATB - XPB) * 256 + tid;
  if (f < 8192) {                     // W1l frags [0,4096), W1r [4096,8192)
    const float* W = (f < 4096) ? W1l : W1r;
    unsigned short* P = (f < 4096) ? w1lp : w1rp;
    f &= 4095;
    const int nt = f >> 8, kb = (f >> 6) & 3, lane = f & 63;
    const int col = nt * 16 + (lane & 15);
    const int k0 = kb * 32 + (lane >> 4) * 8;
    ushortx8 u8;
#pragma unroll
    for (int j = 0; j < 8; ++j) u8[j] = f2bf(W[(size_t)(k0 + j) * C1 + col]);
    *reinterpret_cast<ushortx8*>(P + (size_t)f * 8) = u8;
  } else {                            // W2l frags [0,1024), W2r [1024,2048)
    f -= 8192;
    const float* W = (f < 1024) ? W2l : W2r;
    unsigned short* P = (f < 1024) ? w2lp : w2rp;
    f &= 1023;
    const int nt = f >> 9, kb = (f >> 6) & 7, lane = f & 63;
    const int col = nt * 16 + (lane & 15);
    const int k0 = kb * 32 + (lane >> 4) * 8;
    ushortx8 u8;
#pragma unroll
    for (int j = 0; j < 8; ++j) u8[j] = f2bf(W[(size_t)(k0 + j) * HIDC + col]);
    *reinterpret_cast<ushortx8*>(P + (size_t)f * 8) = u8;
  }
}

// ---------- coalesced fragment load: lane i reads base + i*16B ----------
__device__ __forceinline__ bf16x8 ldfrag(const unsigned short* base, int lane) {
  uintx4 raw = *reinterpret_cast<const uintx4*>(base + (size_t)lane * 8);
  return __builtin_bit_cast(bf16x8, raw);
}

// ---------- 32-row single-output GEMM from fragment-packed operands ----------
template <int KB, int NCOLS>
__device__ __forceinline__ void gemm_body32(
    int u, int lane, const unsigned short* __restrict__ Ap,
    const unsigned short* __restrict__ Bp, unsigned short* __restrict__ C) {
  const int lo = lane & 15;
  const int q  = lane >> 4;
  const int r0 = u * 32;
  const bool two = (r0 + 16) < N_NODES;   // tail unit: rg1 is pad

  bf16x8 af[2][KB];
#pragma unroll
  for (int rg = 0; rg < 2; ++rg)
#pragma unroll
    for (int kb = 0; kb < KB; ++kb)
      af[rg][kb] = ldfrag(Ap + ((size_t)(u * 2 + rg) * KB + kb) * 64 * 8, lane);

#pragma unroll 4
  for (int nt = 0; nt < NCOLS / 16; ++nt) {
    bf16x8 b[KB];
#pragma unroll
    for (int kb = 0; kb < KB; ++kb)
      b[kb] = ldfrag(Bp + ((size_t)nt * KB + kb) * 64 * 8, lane);
    floatx4 acc0 = {0.f, 0.f, 0.f, 0.f};
    floatx4 acc1 = {0.f, 0.f, 0.f, 0.f};
#pragma unroll
    for (int kb = 0; kb < KB; ++kb) {
      acc0 = __builtin_amdgcn_mfma_f32_16x16x32_bf16(af[0][kb], b[kb], acc0, 0, 0, 0);
      acc1 = __builtin_amdgcn_mfma_f32_16x16x32_bf16(af[1][kb], b[kb], acc1, 0, 0, 0);
    }
    // C/D layout: col = lane&15, row = (lane>>4)*4 + reg   [m89-verified]
#pragma unroll
    for (int r = 0; r < 4; ++r) {
      C[(size_t)(r0 + q * 4 + r) * NCOLS + nt * 16 + lo] = f2bf(acc0[r]);
      if (two)
        C[(size_t)(r0 + 16 + q * 4 + r) * NCOLS + nt * 16 + lo] = f2bf(acc1[r]);
    }
  }
}

// ---------- GEMM1: xpack x (w1lp,w1rp) -> xl1, xr1 (row-major) ----------
__global__ __launch_bounds__(256) void k_gemm1(
    const unsigned short* __restrict__ Ap,
    const unsigned short* __restrict__ B0, const unsigned short* __restrict__ B1,
    unsigned short* __restrict__ C0, unsigned short* __restrict__ C1_) {
  const int wave = threadIdx.x >> 6;
  const int lane = threadIdx.x & 63;
  const int unit = blockIdx.x * 4 + wave;
  if (unit >= 2 * NU32) return;
  const int o = (unit >= NU32) ? 1 : 0;
  gemm_body32<4, C1>(unit - o * NU32, lane, Ap, o ? B1 : B0, o ? C1_ : C0);
}

// ---------- GEMM2: h1pack x (w2lp,w2rp) -> xl2, xr2 (row-major) ----------
__global__ __launch_bounds__(256) void k_gemm2(
    const unsigned short* __restrict__ Ap,
    const unsigned short* __restrict__ B0, const unsigned short* __restrict__ B1,
    unsigned short* __restrict__ C0, unsigned short* __restrict__ C1_) {
  const int wave = threadIdx.x >> 6;
  const int lane = threadIdx.x & 63;
  const int unit = blockIdx.x * 4 + wave;
  if (unit >= 2 * NU32) return;
  const int o = (unit >= NU32) ? 1 : 0;
  gemm_body32<8, HIDC>(unit - o * NU32, lane, Ap, o ? B1 : B0, o ? C1_ : C0);
}

// ---------- GAT layer 1 (round-1 proven structure — empirical optimum) ----------
// One wave per dst (4/block); half h = lane>>5 processes alternating edges;
// lane w = lane&31 owns channels w*8..w*8+7. 2-deep ping-pong gather prefetch.
// No softmax max-tracking (scores tiny; med3 clamp insurance). log2e in att.
// Output written directly in GEMM2 A-fragment order to h1pack.
// NOTE: width-4 passes (r3), 3-deep prefetch (r9), dst-pairing (r10) all
// measured neutral-to-worse — ILP here trades ~1:1 against occupancy.
__global__ __launch_bounds__(256) void k_gat1(
    const unsigned short* __restrict__ xl1, const unsigned short* __restrict__ xr1,
    const float* __restrict__ att1, const float* __restrict__ b1,
    const int* __restrict__ deg, const int* __restrict__ esrc,
    unsigned short* __restrict__ h1pack) {
  const int wave = threadIdx.x >> 6;
  const int lane = threadIdx.x & 63;
  const int dst = blockIdx.x * 4 + wave;
  if (dst >= N_NODES) return;
  const int h = lane >> 5;
  const int w = lane & 31;
  const int cb = w * 8;

  floatx2 xr2v[4], att2v[4];
  {
    uintx4 r = *reinterpret_cast<const uintx4*>(xr1 + (size_t)dst * C1 + cb);
    floatx4 a0 = *reinterpret_cast<const floatx4*>(att1 + cb);
    floatx4 a1 = *reinterpret_cast<const floatx4*>(att1 + cb + 4);
#pragma unroll
    for (int j = 0; j < 4; ++j) xr2v[j] = bf2x2(r[j]);
    att2v[0] = floatx2{a0.x, a0.y} * LOG2E;
    att2v[1] = floatx2{a0.z, a0.w} * LOG2E;
    att2v[2] = floatx2{a1.x, a1.y} * LOG2E;
    att2v[3] = floatx2{a1.z, a1.w} * LOG2E;
  }

  const int n = min(deg[dst], SEG_CAP);
  const int* __restrict__ ep = esrc + ((size_t)dst << 6);

  float l = 0.f;
  floatx2 acc2[4] = {{0.f, 0.f}, {0.f, 0.f}, {0.f, 0.f}, {0.f, 0.f}};

  auto process = [&](uintx4 cur) {
    floatx2 xs2[4];
    floatx2 v2 = {0.f, 0.f};
#pragma unroll
    for (int j = 0; j < 4; ++j) {
      xs2[j] = bf2x2(cur[j]);
      floatx2 s2 = xs2[j] + xr2v[j];
      floatx2 e2 = __builtin_elementwise_max(s2, s2 * NEG_SLOPE);   // leaky
      v2 = __builtin_elementwise_fma(e2, att2v[j], v2);
    }
    float v = v2.x + v2.y;
    v += __shfl_xor(v, 1);
    v += __shfl_xor(v, 2);          // 4-lane group = one head
    v = __builtin_amdgcn_fmed3f(v, -100.f, 100.f);
    const float p = __builtin_amdgcn_exp2f(v);   // exp(score): log2e in att
    l += p;
    const floatx2 p2 = {p, p};
#pragma unroll
    for (int j = 0; j < 4; ++j)
      acc2[j] = __builtin_elementwise_fma(p2, xs2[j], acc2[j]);
  };

  // ping-pong double-buffered gather, 2 iterations of prefetch depth
  uintx4 bufa = {0u, 0u, 0u, 0u}, bufb = {0u, 0u, 0u, 0u};
  if (h < n)
    bufa = *reinterpret_cast<const uintx4*>(xl1 + (size_t)ep[h] * C1 + cb);
  if (h + 2 < n)
    bufb = *reinterpret_cast<const uintx4*>(xl1 + (size_t)ep[h + 2] * C1 + cb);
  int i = h;
  while (i < n) {
    process(bufa);
    if (i + 4 < n)
      bufa = *reinterpret_cast<const uintx4*>(xl1 + (size_t)ep[i + 4] * C1 + cb);
    i += 2;
    if (i >= n) break;
    process(bufb);
    if (i + 4 < n)
      bufb = *reinterpret_cast<const uintx4*>(xl1 + (size_t)ep[i + 4] * C1 + cb);
    i += 2;
  }

  // merge the two halves (plain sums; no max bookkeeping)
  l += __shfl_xor(l, 32);
#pragma unroll
  for (int j = 0; j < 4; ++j) {
    acc2[j].x += __shfl_xor(acc2[j].x, 32);
    acc2[j].y += __shfl_xor(acc2[j].y, 32);
  }

  if (h == 0) {
    const float inv = 1.f / fmaxf(l, 1e-16f);
    ushortx8 ob;
#pragma unroll
    for (int j = 0; j < 4; ++j) {
      float z0 = acc2[j].x * inv + b1[cb + 2 * j];
      float z1 = acc2[j].y * inv + b1[cb + 2 * j + 1];
      z0 = z0 > 0.f ? z0 : (__expf(z0) - 1.f);   // ELU
      z1 = z1 > 0.f ? z1 : (__expf(z1) - 1.f);
      ob[2 * j]     = f2bf(z0);
      ob[2 * j + 1] = f2bf(z1);
    }
    // fragment-order store for GEMM2 A
    const size_t frag = ((size_t)(dst >> 4) * 8 + (cb >> 5)) * 64
                      + ((cb >> 3) & 3) * 16 + (dst & 15);
    *reinterpret_cast<ushortx8*>(h1pack + frag * 8) = ob;
  }
}

// ---------- GAT layer 2 (1 head, 32 ch) fused with final linear [32x16] ----------
__global__ __launch_bounds__(256) void k_gat2(
    const unsigned short* __restrict__ xl2, const unsigned short* __restrict__ xr2,
    const float* __restrict__ att2, const float* __restrict__ b2,
    const float* __restrict__ Wlin, const float* __restrict__ blin,
    const int* __restrict__ deg, const int* __restrict__ esrc,
    float* __restrict__ out) {
  __shared__ float sh[4][32];
  const int wave = threadIdx.x >> 6;
  const int lane = threadIdx.x & 63;
  const int dst = blockIdx.x * 4 + wave;
  if (dst >= N_NODES) return;
  const int o8 = lane >> 3;   // edge slot (8 edges in flight)
  const int w = lane & 7;     // channel group
  const int cb = w * 4;       // 4 ch = 2 bf16x2 pairs

  floatx2 xr2v[2], att2v[2];
  {
    uintx2 r = *reinterpret_cast<const uintx2*>(xr2 + (size_t)dst * HIDC + cb);
    floatx4 a = *reinterpret_cast<const floatx4*>(att2 + cb);
    xr2v[0] = bf2x2(r[0]);
    xr2v[1] = bf2x2(r[1]);
    att2v[0] = floatx2{a.x, a.y} * LOG2E;
    att2v[1] = floatx2{a.z, a.w} * LOG2E;
  }

  const int n = min(deg[dst], SEG_CAP);
  const int* __restrict__ ep = esrc + ((size_t)dst << 6);

  float l = 0.f;
  floatx2 acc2[2] = {{0.f, 0.f}, {0.f, 0.f}};

  auto process = [&](uintx2 cur) {
    floatx2 xs2[2];
    floatx2 v2 = {0.f, 0.f};
#pragma unroll
    for (int j = 0; j < 2; ++j) {
      xs2[j] = bf2x2(cur[j]);
      floatx2 s2 = xs2[j] + xr2v[j];
      floatx2 e2 = __builtin_elementwise_max(s2, s2 * NEG_SLOPE);
      v2 = __builtin_elementwise_fma(e2, att2v[j], v2);
    }
    float v = v2.x + v2.y;
    v += __shfl_xor(v, 1);
    v += __shfl_xor(v, 2);
    v += __shfl_xor(v, 4);          // 8-lane group = full 32-ch head
    v = __builtin_amdgcn_fmed3f(v, -100.f, 100.f);
    const float p = __builtin_amdgcn_exp2f(v);
    l += p;
    const floatx2 p2 = {p, p};
#pragma unroll
    for (int j = 0; j < 2; ++j)
      acc2[j] = __builtin_elementwise_fma(p2, xs2[j], acc2[j]);
  };

  uintx2 bufa = {0u, 0u}, bufb = {0u, 0u};
  if (o8 < n)
    bufa = *reinterpret_cast<const uintx2*>(xl2 + (size_t)ep[o8] * HIDC + cb);
  if (o8 + 8 < n)
    bufb = *reinterpret_cast<const uintx2*>(xl2 + (size_t)ep[o8 + 8] * HIDC + cb);
  int i = o8;
  while (i < n) {
    process(bufa);
    if (i + 16 < n)
      bufa = *reinterpret_cast<const uintx2*>(xl2 + (size_t)ep[i + 16] * HIDC + cb);
    i += 8;
    if (i >= n) break;
    process(bufb);
    if (i + 16 < n)
      bufb = *reinterpret_cast<const uintx2*>(xl2 + (size_t)ep[i + 16] * HIDC + cb);
    i += 8;
  }

  // merge 8 octets (plain sums)
#pragma unroll
  for (int k = 8; k < 64; k <<= 1) {
    l += __shfl_xor(l, k);
#pragma unroll
    for (int j = 0; j < 2; ++j) {
      acc2[j].x += __shfl_xor(acc2[j].x, k);
      acc2[j].y += __shfl_xor(acc2[j].y, k);
    }
  }

  if (o8 == 0) {
    const float inv = 1.f / fmaxf(l, 1e-16f);
#pragma unroll
    for (int j = 0; j < 2; ++j) {
      float z0 = acc2[j].x * inv + b2[cb + 2 * j];
      float z1 = acc2[j].y * inv + b2[cb + 2 * j + 1];
      z0 = z0 > 0.f ? z0 : (__expf(z0) - 1.f);   // ELU
      z1 = z1 > 0.f ? z1 : (__expf(z1) - 1.f);
      sh[wave][cb + 2 * j]     = z0;
      sh[wave][cb + 2 * j + 1] = z1;
    }
  }
  if (lane < OUTC) {
    float o = blin[lane];
#pragma unroll
    for (int k = 0; k < 32; ++k)
      o = fmaf(sh[wave][k], Wlin[k * OUTC + lane], o);
    out[(size_t)dst * OUTC + lane] = o;
  }
}

static inline int cdiv(int a, int b) { return (a + b - 1) / b; }

extern "C" void kernel_launch(void* const* d_in, const int* in_sizes, int n_in,
                              void* d_out, int out_size, void* d_ws, size_t ws_size,
                              hipStream_t stream) {
  const float* x    = (const float*)d_in[0];
  const int*   ei   = (const int*)d_in[1];
  const float* W1l  = (const float*)d_in[2];
  const float* W1r  = (const float*)d_in[3];
  const float* att1 = (const float*)d_in[4];
  const float* b1   = (const float*)d_in[5];
  const float* W2l  = (const float*)d_in[6];
  const float* W2r  = (const float*)d_in[7];
  const float* att2 = (const float*)d_in[8];
  const float* b2   = (const float*)d_in[9];
  const float* Wlin = (const float*)d_in[10];
  const float* blin = (const float*)d_in[11];
  float* out = (float*)d_out;

  char* w = (char*)d_ws;
  auto alloc = [&](size_t bytes) -> char* {
    char* p = w;
    w += (bytes + 255) & ~(size_t)255;
    return p;
  };
  // region A: xl1 (row-major, GEMM1 out), later reused for xl2+xr2 (GEMM2 out)
  char* regionA = alloc((size_t)N_NODES * C1 * 2);          // 25.6 MB
  unsigned short* xl1 = (unsigned short*)regionA;
  unsigned short* xl2 = (unsigned short*)regionA;                           // 3.2 MB
  unsigned short* xr2 = (unsigned short*)(regionA + (size_t)N_NODES * HIDC * 2 + 256);
  unsigned short* xr1 = (unsigned short*)alloc((size_t)N_NODES * C1 * 2);   // 25.6 MB
  // fragment-packed operands
  unsigned short* xpack  = (unsigned short*)alloc((size_t)U16PAD * 4 * 64 * 8 * 2); // 12.8 MB
  unsigned short* h1pack = (unsigned short*)alloc((size_t)U16PAD * 8 * 64 * 8 * 2); // 25.6 MB
  unsigned short* w1lp = (unsigned short*)alloc((size_t)4096 * 8 * 2);  // 64 KB
  unsigned short* w1rp = (unsigned short*)alloc((size_t)4096 * 8 * 2);
  unsigned short* w2lp = (unsigned short*)alloc((size_t)1024 * 8 * 2);  // 16 KB
  unsigned short* w2rp = (unsigned short*)alloc((size_t)1024 * 8 * 2);
  int* deg    = (int*)alloc((size_t)N_NODES * 4);
  int* esrc   = (int*)alloc((size_t)N_NODES * SEG_CAP * 4);   // 12.8 MB

  hipMemsetAsync(deg, 0, (size_t)N_NODES * 4, stream);

  // 4-edge-batched CSR scatter (long pole first) + x frag-pack + weight frag-packs
  k_prep<<<PREPB, 256, 0, stream>>>(ei, x, xpack, W1l, W1r, W2l, W2r,
                                    w1lp, w1rp, w2lp, w2rp, deg, esrc);

  k_gemm1<<<GBLK, 256, 0, stream>>>(xpack, w1lp, w1rp, xl1, xr1);

  k_gat1<<<cdiv(N_NODES, 4), 256, 0, stream>>>(xl1, xr1, att1, b1,
                                               deg, esrc, h1pack);

  k_gemm2<<<GBLK, 256, 0, stream>>>(h1pack, w2lp, w2rp, xl2, xr2);

  k_gat2<<<cdiv(N_NODES, 4), 256, 0, stream>>>(xl2, xr2, att2, b2, Wlin, blin,
                                               deg, esrc, out);
}